// Round 2
// baseline (282.866 us; speedup 1.0000x reference)
//
#include <hip/hip_runtime.h>
#include <math.h>

// Tensor-field-network decoder: B=2, N=192, 3 conv layers (2 gated + 1 final).
// Round-2 structure:
//   tfn_pre:    per-pair Y[8] + per-layer radial hidden h[32] (geometry-only, hoisted)
//   tfn_stage1: per (atom, neighbor-split) partial M[32][TC] accumulation (grid 1536)
//   tfn_stage2: sum 4 partials + wout contraction + gating (grid 384)
// Falls back to the verified round-1 monolithic kernel if ws_size is too small.

#define NN 192
#define BB 2
#define HHID 32
#define NBASIS 10
#define SPLIT 4
#define NS (NN / SPLIT)   // 48 neighbors per stage1 block

__device__ __forceinline__ float relu_r(float x) {
    return fmaxf(x, 0.0f) * 1.4142135623730951f;
}
__device__ __forceinline__ float sigmoid_r(float x) {
    return (1.0f / (1.0f + expf(-x))) * 1.84623f;
}

// ---------------------------------------------------------------------------
// Precompute kernel: per pair (z,a,b): Y[8]; per layer: h[32].
// grid = BB*NN*NN*32/256 blocks of 256.
// ---------------------------------------------------------------------------
__global__ __launch_bounds__(256) void tfn_pre(
    const float* __restrict__ geo,
    const float* __restrict__ w00, const float* __restrict__ b00,
    const float* __restrict__ w01, const float* __restrict__ b01,
    const float* __restrict__ w02, const float* __restrict__ b02,
    float* __restrict__ Yg, float* __restrict__ h0g,
    float* __restrict__ h1g, float* __restrict__ h2g)
{
    const int gid = blockIdx.x * 256 + threadIdx.x;
    const int pair = gid >> 5, j = gid & 31;
    const int z = pair / (NN * NN);
    const int rem = pair % (NN * NN);
    const int a = rem / NN, b = rem % NN;
    const float* ga = &geo[(z * NN + a) * 3];
    const float* gb = &geo[(z * NN + b) * 3];
    float rx = ga[0] - gb[0], ry = ga[1] - gb[1], rz = ga[2] - gb[2];
    float r = sqrtf(rx * rx + ry * ry + rz * rz + 1e-12f);
    float inv = 1.0f / fmaxf(r, 1e-6f);
    float ux = rx * inv, uy = ry * inv, uz = rz * inv;

    float bas[NBASIS];
#pragma unroll
    for (int k = 0; k < NBASIS; ++k) {
        float dg = r * 2.25f - (float)k;  // (r - k*step)/step, step = 4/9
        float v = 0.0f;
        if (fabsf(dg) < 1.0f) {
            float cc = cosf(1.5707963267948966f * dg);
            v = cc * cc;
        }
        bas[k] = v;
    }
    const float isq10 = 0.31622776601683794f;
    float s0 = 0.0f, s1 = 0.0f, s2 = 0.0f;
#pragma unroll
    for (int k = 0; k < NBASIS; ++k) {
        s0 += bas[k] * w00[k * HHID + j];
        s1 += bas[k] * w01[k * HHID + j];
        s2 += bas[k] * w02[k * HHID + j];
    }
    h0g[pair * 32 + j] = relu_r(s0 * isq10 + b00[j]);
    h1g[pair * 32 + j] = relu_r(s1 * isq10 + b01[j]);
    h2g[pair * 32 + j] = relu_r(s2 * isq10 + b02[j]);

    if (j < 8) {
        float y;
        switch (j) {
            case 0: y = 0.4886025119029199f * uy; break;
            case 1: y = 0.4886025119029199f * uz; break;
            case 2: y = 0.4886025119029199f * ux; break;
            case 3: y = 1.0925484305920792f * ux * uy; break;
            case 4: y = 1.0925484305920792f * uy * uz; break;
            case 5: y = 0.31539156525252005f * (2.0f * uz * uz - ux * ux - uy * uy); break;
            case 6: y = 1.0925484305920792f * ux * uz; break;
            default: y = 0.5462742152960396f * (ux * ux - uy * uy); break;
        }
        Yg[pair * 8 + j] = y;
    }
}

// ---------------------------------------------------------------------------
// Stage 1: partial M[32][TC] over 48 neighbors. grid = BB*NN*SPLIT.
// ---------------------------------------------------------------------------
template <int LAYER>
__global__ __launch_bounds__(256, 4) void tfn_stage1(
    const float* __restrict__ fin0,  // [B,N,16]
    const float* __restrict__ fin1,  // [B,N,8,3] (unused L0)
    const float* __restrict__ Yg,    // [B*N*N, 8]
    const float* __restrict__ hg,    // [B*N*N, 32]
    float* __restrict__ part)        // [B*N*SPLIT, 32*TC]
{
    constexpr int TC   = (LAYER == 0) ? 64 : 144;
    constexpr int CPT  = TC / 8;
    constexpr int CPTT = TC / 16;

    const int tid  = threadIdx.x;
    const int blk  = blockIdx.x;
    const int sp   = blk & (SPLIT - 1);
    const int atom = blk >> 2;          // z*NN + a
    const int z    = atom / NN;
    const int nb0  = sp * NS;           // first neighbor of this block

    __shared__ float f0S[NS * 16];
    __shared__ float f1S[(LAYER == 0) ? 1 : (NS * 24)];
    __shared__ float YC[2 * 16 * 8];
    __shared__ float hC[2 * 16 * 32];
    __shared__ float tC[16 * TC];

    const float s = 0.07216878364870323f;  // 1/sqrt(192)

    for (int i = tid; i < NS * 16; i += 256) {
        float v = fin0[(z * NN + nb0) * 16 + i];
        if (LAYER == 0) v *= s;
        f0S[i] = v;
    }
    if constexpr (LAYER != 0) {
        for (int i = tid; i < NS * 24; i += 256) f1S[i] = fin1[(z * NN + nb0) * 24 + i];
    }

    const int pb0 = atom * NN + nb0;  // first pair index of this block
    // preload chunk 0 h/Y
    {
        hC[tid]       = hg[pb0 * 32 + tid];
        hC[tid + 256] = hg[pb0 * 32 + tid + 256];
        if (tid < 128) YC[tid] = Yg[pb0 * 8 + tid];
    }

    float Macc[CPT];
#pragma unroll
    for (int j = 0; j < CPT; ++j) Macc[j] = 0.0f;
    const int hh  = tid >> 3;
    const int cg0 = (tid & 7) * CPT;

    __syncthreads();

    for (int cb = 0; cb < NS / 16; ++cb) {
        const int cur = cb & 1, nxt = cur ^ 1;

        // ---- T columns: 16 b x TC ----
        {
            const int bl = tid >> 4, cg = tid & 15;
            const int bLoc = cb * 16 + bl;            // local neighbor index in slice
            const float* Yb = &YC[cur * 128 + bl * 8];
#pragma unroll
            for (int jj = 0; jj < CPTT; ++jj) {
                int c = cg * CPTT + jj;
                float val;
                if constexpr (LAYER == 0) {
                    if (c < 16) {
                        val = 0.28209479177387814f * f0S[bLoc * 16 + c];         // (0,0,0)
                    } else {
                        int q = c - 16, v = q / 3, i2 = q % 3;                   // (1,0,1)
                        val = Yb[i2] * f0S[bLoc * 16 + v] * 0.5773502691896258f;
                    }
                } else {
                    if (c < 16) {
                        val = 0.28209479177387814f * f0S[bLoc * 16 + c];         // (0,0,0)
                    } else if (c < 24) {
                        int v = c - 16;                                          // (0,1,1)
                        const float* f = &f1S[(bLoc * 8 + v) * 3];
                        val = (f[0] * Yb[0] + f[1] * Yb[1] + f[2] * Yb[2]) * 0.5773502691896258f;
                    } else if (c < 72) {
                        int q = c - 24, v = q / 3, i2 = q % 3;                   // (1,0,1)
                        val = Yb[i2] * f0S[bLoc * 16 + v] * 0.5773502691896258f;
                    } else if (c < 96) {
                        int q = c - 72, v = q / 3, i2 = q % 3;                   // (1,1,0)
                        val = f1S[(bLoc * 8 + v) * 3 + i2] * (0.28209479177387814f * 0.5773502691896258f);
                    } else if (c < 120) {
                        int q = c - 96, v = q / 3, i2 = q % 3;                   // (1,1,1) cross
                        const float* f = &f1S[(bLoc * 8 + v) * 3];
                        int i1 = (i2 + 1) % 3, i3 = (i2 + 2) % 3;
                        val = (f[i1] * Yb[i3] - f[i3] * Yb[i1]) * 0.4082482904638631f;
                    } else {
                        int q = c - 120, v = q / 3, i2 = q % 3;                  // (1,1,2)
                        const float* f = &f1S[(bLoc * 8 + v) * 3];
                        const float D  = 0.31622776601683794f;   // d/||m||
                        const float Bc = 0.18257418583505536f;   // b/||m||
                        float Y20 = Yb[3], Y21 = Yb[4], Y22 = Yb[5], Y23 = Yb[6], Y24 = Yb[7];
                        if (i2 == 0)      val = D * (Y20 * f[2] + Y21 * f[1]) - (Bc * Y22 + D * Y24) * f[0];
                        else if (i2 == 1) val = D * (Y21 * f[0] + Y23 * f[2]) + 2.0f * Bc * Y22 * f[1];
                        else              val = D * (Y20 * f[0] + Y23 * f[1] + Y24 * f[2]) - Bc * Y22 * f[2];
                    }
                }
                tC[bl * TC + c] = val;
            }
        }

        // ---- prefetch next chunk's h/Y into the other buffer ----
        if (cb + 1 < NS / 16) {
            const int pbn = pb0 + (cb + 1) * 16;
            hC[nxt * 512 + tid]       = hg[pbn * 32 + tid];
            hC[nxt * 512 + tid + 256] = hg[pbn * 32 + tid + 256];
            if (tid < 128) YC[nxt * 128 + tid] = Yg[pbn * 8 + tid];
        }
        __syncthreads();

        // ---- rank-16 update of M ----
#pragma unroll 4
        for (int bl = 0; bl < 16; ++bl) {
            float hv = hC[cur * 512 + bl * 32 + hh];
#pragma unroll
            for (int j = 0; j < CPT; ++j) Macc[j] += hv * tC[bl * TC + cg0 + j];
        }
        __syncthreads();
    }

    // ---- write partial M ----
    const int obase = blk * (32 * TC) + hh * TC + cg0;
#pragma unroll
    for (int j = 0; j < CPT; ++j) part[obase + j] = Macc[j];
}

// ---------------------------------------------------------------------------
// Stage 2: sum SPLIT partials, contract with wout, gate, store. grid = BB*NN.
// ---------------------------------------------------------------------------
template <int LAYER>
__global__ __launch_bounds__(256) void tfn_stage2(
    const float* __restrict__ part,
    const float* __restrict__ wout,
    float* __restrict__ o0, float* __restrict__ o1)
{
    constexpr int TC = (LAYER == 0) ? 64 : 144;
    constexpr int TW = (LAYER == 0) ? 512 : (LAYER == 1 ? 896 : 128);

    const int tid = threadIdx.x;
    const int atom = blockIdx.x;  // z*NN + a

    __shared__ float Mlds[32 * TC];
    __shared__ float outS[32];

    for (int idx = tid; idx < 32 * TC; idx += 256) {
        float su = 0.0f;
#pragma unroll
        for (int sp = 0; sp < SPLIT; ++sp)
            su += part[(atom * SPLIT + sp) * (32 * TC) + idx];
        Mlds[idx] = su;
    }
    __syncthreads();

    const float s   = 0.07216878364870323f;  // 1/sqrt(192)
    const float i32 = 0.1767766952966369f;   // 1/sqrt(32)

    if constexpr (LAYER == 0) {
        const float sc = i32 * 0.25f;
        float o1v = 0.0f;
        if (tid < 24) {
            float acc = 0.0f;
            for (int h2 = 0; h2 < 32; ++h2) {
                const float* wr = &wout[h2 * TW + tid * 16];
                const float* mr = &Mlds[h2 * TC];
#pragma unroll
                for (int v = 0; v < 16; ++v) acc += wr[v] * mr[v];
            }
            outS[tid] = acc * sc;
        } else if (tid >= 32 && tid < 56) {
            int idx = tid - 32, u = idx / 3, i2 = idx % 3;
            float acc = 0.0f;
            for (int h2 = 0; h2 < 32; ++h2) {
                const float* wr = &wout[h2 * TW + 384 + u * 16];
                const float* mr = &Mlds[h2 * TC + 16 + i2];
#pragma unroll
                for (int v = 0; v < 16; ++v) acc += wr[v] * mr[v * 3];
            }
            o1v = acc * sc;
        }
        __syncthreads();
        if (tid < 16) {
            o0[atom * 16 + tid] = relu_r(outS[tid]) * s;
        } else if (tid >= 32 && tid < 56) {
            int idx = tid - 32, u = idx / 3, i2 = idx % 3;
            float g = sigmoid_r(outS[16 + u]);
            o1[(atom * 8 + u) * 3 + i2] = o1v * g * s;
        }
    } else if constexpr (LAYER == 1) {
        float o1v = 0.0f;
        if (tid < 24) {
            float aA = 0.0f, aB = 0.0f;
            for (int h2 = 0; h2 < 32; ++h2) {
                const float* wr = &wout[h2 * TW];
                const float* mr = &Mlds[h2 * TC];
#pragma unroll
                for (int v = 0; v < 16; ++v) aA += wr[tid * 16 + v] * mr[v];
#pragma unroll
                for (int v = 0; v < 8; ++v) aB += wr[384 + tid * 8 + v] * mr[16 + v];
            }
            outS[tid] = (aA * i32 + aB * 0.25f) * i32;
        } else if (tid >= 32 && tid < 56) {
            int idx = tid - 32, u = idx / 3, i2 = idx % 3;
            float aA = 0.0f, aB = 0.0f;
            for (int h2 = 0; h2 < 32; ++h2) {
                const float* wr = &wout[h2 * TW];
                const float* mr = &Mlds[h2 * TC];
#pragma unroll
                for (int v = 0; v < 16; ++v) aA += wr[576 + u * 16 + v] * mr[24 + v * 3 + i2];
#pragma unroll
                for (int v = 0; v < 8; ++v)
                    aB += wr[704 + u * 8 + v] * mr[72 + v * 3 + i2]
                        + wr[768 + u * 8 + v] * mr[96 + v * 3 + i2]
                        + wr[832 + u * 8 + v] * mr[120 + v * 3 + i2];
            }
            o1v = (aA * 0.125f + aB * i32) * i32;
        }
        __syncthreads();
        if (tid < 16) {
            o0[atom * 16 + tid] = relu_r(outS[tid]) * s;
        } else if (tid >= 32 && tid < 56) {
            int idx = tid - 32, u = idx / 3, i2 = idx % 3;
            float g = sigmoid_r(outS[16 + u]);
            o1[(atom * 8 + u) * 3 + i2] = o1v * g * s;
        }
    } else {  // LAYER == 2: final conv; write [B,N,2,4] interleaved
        if (tid < 2) {
            float aA = 0.0f, aB = 0.0f;
            for (int h2 = 0; h2 < 32; ++h2) {
                const float* wr = &wout[h2 * TW];
                const float* mr = &Mlds[h2 * TC];
#pragma unroll
                for (int v = 0; v < 16; ++v) aA += wr[tid * 16 + v] * mr[v];
#pragma unroll
                for (int v = 0; v < 8; ++v) aB += wr[32 + tid * 8 + v] * mr[16 + v];
            }
            o0[atom * 8 + tid * 4] = (aA * i32 + aB * 0.25f) * i32;
        } else if (tid >= 32 && tid < 38) {
            int idx = tid - 32, u = idx / 3, i2 = idx % 3;
            float aA = 0.0f, aB = 0.0f;
            for (int h2 = 0; h2 < 32; ++h2) {
                const float* wr = &wout[h2 * TW];
                const float* mr = &Mlds[h2 * TC];
#pragma unroll
                for (int v = 0; v < 16; ++v) aA += wr[48 + u * 16 + v] * mr[24 + v * 3 + i2];
#pragma unroll
                for (int v = 0; v < 8; ++v)
                    aB += wr[80 + u * 8 + v] * mr[72 + v * 3 + i2]
                        + wr[96 + u * 8 + v] * mr[96 + v * 3 + i2]
                        + wr[112 + u * 8 + v] * mr[120 + v * 3 + i2];
            }
            o0[atom * 8 + u * 4 + 1 + i2] = (aA * 0.125f + aB * i32) * i32;
        }
    }
}

// ---------------------------------------------------------------------------
// Fallback: verified round-1 monolithic kernel (used when ws_size is small).
// ---------------------------------------------------------------------------
template <int LAYER>
__global__ __launch_bounds__(256) void tfn_layer_mono(
    const float* __restrict__ geo,
    const float* __restrict__ fin0,
    const float* __restrict__ fin1,
    const float* __restrict__ w0,
    const float* __restrict__ b0g,
    const float* __restrict__ wout,
    float* __restrict__ o0,
    float* __restrict__ o1)
{
    constexpr int TC   = (LAYER == 0) ? 64 : 144;
    constexpr int TW   = (LAYER == 0) ? 512 : (LAYER == 1 ? 896 : 128);
    constexpr int CPT  = TC / 8;
    constexpr int CPTT = TC / 16;

    const int tid = threadIdx.x;
    const int blk = blockIdx.x;
    const int z = blk / NN, a = blk % NN;

    __shared__ float geoL[NN * 3];
    __shared__ float f0L[NN * 16];
    __shared__ float f1L[(LAYER == 0) ? 1 : (NN * 24)];
    __shared__ float w0L[NBASIS * HHID];
    __shared__ float b0L[HHID];
    __shared__ float YC[16 * 8];
    __shared__ float basC[16 * NBASIS];
    __shared__ float hC[16 * HHID];
    __shared__ float tC[16 * TC];
    __shared__ float Mlds[HHID * TC];
    __shared__ float outS[32];

    const float s = 0.07216878364870323f;

    for (int i = tid; i < NN * 3; i += 256) geoL[i] = geo[z * NN * 3 + i];
    for (int i = tid; i < NN * 16; i += 256) {
        float v = fin0[z * NN * 16 + i];
        if (LAYER == 0) v *= s;
        f0L[i] = v;
    }
    if constexpr (LAYER != 0) {
        for (int i = tid; i < NN * 24; i += 256) f1L[i] = fin1[z * NN * 24 + i];
    }
    for (int i = tid; i < NBASIS * HHID; i += 256) w0L[i] = w0[i];
    if (tid < HHID) b0L[tid] = b0g[tid];
    __syncthreads();

    const float ax = geoL[a * 3 + 0], ay = geoL[a * 3 + 1], az = geoL[a * 3 + 2];

    float Macc[CPT];
#pragma unroll
    for (int j = 0; j < CPT; ++j) Macc[j] = 0.0f;
    const int hh  = tid >> 3;
    const int cg0 = (tid & 7) * CPT;

    const float inv_sqrt10 = 0.31622776601683794f;

    for (int cb = 0; cb < NN / 16; ++cb) {
        {
            const int bl = tid & 15, item = tid >> 4;
            const int b = cb * 16 + bl;
            float rx = ax - geoL[b * 3 + 0];
            float ry = ay - geoL[b * 3 + 1];
            float rz = az - geoL[b * 3 + 2];
            float r2 = rx * rx + ry * ry + rz * rz + 1e-12f;
            float r = sqrtf(r2);
            float inv = 1.0f / fmaxf(r, 1e-6f);
            float ux = rx * inv, uy = ry * inv, uz = rz * inv;
            if (item < NBASIS) {
                float dg = r * 2.25f - (float)item;
                float bas = 0.0f;
                if (fabsf(dg) < 1.0f) {
                    float cc = cosf(1.5707963267948966f * dg);
                    bas = cc * cc;
                }
                basC[bl * NBASIS + item] = bas;
            } else if (item == 10) {
                YC[bl * 8 + 0] = 0.4886025119029199f * uy;
                YC[bl * 8 + 1] = 0.4886025119029199f * uz;
                YC[bl * 8 + 2] = 0.4886025119029199f * ux;
            } else if (item == 11) {
                YC[bl * 8 + 3] = 1.0925484305920792f * ux * uy;
                YC[bl * 8 + 4] = 1.0925484305920792f * uy * uz;
                YC[bl * 8 + 5] = 0.31539156525252005f * (2.0f * uz * uz - ux * ux - uy * uy);
                YC[bl * 8 + 6] = 1.0925484305920792f * ux * uz;
                YC[bl * 8 + 7] = 0.5462742152960396f * (ux * ux - uy * uy);
            }
        }
        __syncthreads();

#pragma unroll
        for (int rep = 0; rep < 2; ++rep) {
            int idx = tid + rep * 256;
            int bl = idx >> 5, h2 = idx & 31;
            float su = 0.0f;
#pragma unroll
            for (int k = 0; k < NBASIS; ++k) su += basC[bl * NBASIS + k] * w0L[k * HHID + h2];
            hC[bl * HHID + h2] = relu_r(su * inv_sqrt10 + b0L[h2]);
        }

        {
            const int bl = tid >> 4, cg = tid & 15;
            const int b = cb * 16 + bl;
            const float* Yb = &YC[bl * 8];
#pragma unroll
            for (int jj = 0; jj < CPTT; ++jj) {
                int c = cg * CPTT + jj;
                float val;
                if constexpr (LAYER == 0) {
                    if (c < 16) {
                        val = 0.28209479177387814f * f0L[b * 16 + c];
                    } else {
                        int q = c - 16, v = q / 3, i2 = q % 3;
                        val = Yb[i2] * f0L[b * 16 + v] * 0.5773502691896258f;
                    }
                } else {
                    if (c < 16) {
                        val = 0.28209479177387814f * f0L[b * 16 + c];
                    } else if (c < 24) {
                        int v = c - 16;
                        const float* f = &f1L[(b * 8 + v) * 3];
                        val = (f[0] * Yb[0] + f[1] * Yb[1] + f[2] * Yb[2]) * 0.5773502691896258f;
                    } else if (c < 72) {
                        int q = c - 24, v = q / 3, i2 = q % 3;
                        val = Yb[i2] * f0L[b * 16 + v] * 0.5773502691896258f;
                    } else if (c < 96) {
                        int q = c - 72, v = q / 3, i2 = q % 3;
                        val = f1L[(b * 8 + v) * 3 + i2] * (0.28209479177387814f * 0.5773502691896258f);
                    } else if (c < 120) {
                        int q = c - 96, v = q / 3, i2 = q % 3;
                        const float* f = &f1L[(b * 8 + v) * 3];
                        int i1 = (i2 + 1) % 3, i3 = (i2 + 2) % 3;
                        val = (f[i1] * Yb[i3] - f[i3] * Yb[i1]) * 0.4082482904638631f;
                    } else {
                        int q = c - 120, v = q / 3, i2 = q % 3;
                        const float* f = &f1L[(b * 8 + v) * 3];
                        const float D = 0.31622776601683794f;
                        const float Bc = 0.18257418583505536f;
                        float Y20 = Yb[3], Y21 = Yb[4], Y22 = Yb[5], Y23 = Yb[6], Y24 = Yb[7];
                        if (i2 == 0)      val = D * (Y20 * f[2] + Y21 * f[1]) - (Bc * Y22 + D * Y24) * f[0];
                        else if (i2 == 1) val = D * (Y21 * f[0] + Y23 * f[2]) + 2.0f * Bc * Y22 * f[1];
                        else              val = D * (Y20 * f[0] + Y23 * f[1] + Y24 * f[2]) - Bc * Y22 * f[2];
                    }
                }
                tC[bl * TC + c] = val;
            }
        }
        __syncthreads();

#pragma unroll 4
        for (int bl = 0; bl < 16; ++bl) {
            float hv = hC[bl * HHID + hh];
#pragma unroll
            for (int j = 0; j < CPT; ++j) Macc[j] += hv * tC[bl * TC + cg0 + j];
        }
        __syncthreads();
    }

#pragma unroll
    for (int j = 0; j < CPT; ++j) Mlds[hh * TC + cg0 + j] = Macc[j];
    __syncthreads();

    const float i32 = 0.1767766952966369f;

    if constexpr (LAYER == 0) {
        const float sc = i32 * 0.25f;
        float o1v = 0.0f;
        if (tid < 24) {
            float acc = 0.0f;
            for (int h2 = 0; h2 < 32; ++h2) {
                const float* wr = &wout[h2 * TW + tid * 16];
                const float* mr = &Mlds[h2 * TC];
#pragma unroll
                for (int v = 0; v < 16; ++v) acc += wr[v] * mr[v];
            }
            outS[tid] = acc * sc;
        } else if (tid >= 32 && tid < 56) {
            int idx = tid - 32, u = idx / 3, i2 = idx % 3;
            float acc = 0.0f;
            for (int h2 = 0; h2 < 32; ++h2) {
                const float* wr = &wout[h2 * TW + 384 + u * 16];
                const float* mr = &Mlds[h2 * TC + 16 + i2];
#pragma unroll
                for (int v = 0; v < 16; ++v) acc += wr[v] * mr[v * 3];
            }
            o1v = acc * sc;
        }
        __syncthreads();
        if (tid < 16) {
            o0[(z * NN + a) * 16 + tid] = relu_r(outS[tid]) * s;
        } else if (tid >= 32 && tid < 56) {
            int idx = tid - 32, u = idx / 3, i2 = idx % 3;
            float g = sigmoid_r(outS[16 + u]);
            o1[((z * NN + a) * 8 + u) * 3 + i2] = o1v * g * s;
        }
    } else if constexpr (LAYER == 1) {
        float o1v = 0.0f;
        if (tid < 24) {
            float aA = 0.0f, aB = 0.0f;
            for (int h2 = 0; h2 < 32; ++h2) {
                const float* wr = &wout[h2 * TW];
                const float* mr = &Mlds[h2 * TC];
#pragma unroll
                for (int v = 0; v < 16; ++v) aA += wr[tid * 16 + v] * mr[v];
#pragma unroll
                for (int v = 0; v < 8; ++v) aB += wr[384 + tid * 8 + v] * mr[16 + v];
            }
            outS[tid] = (aA * i32 + aB * 0.25f) * i32;
        } else if (tid >= 32 && tid < 56) {
            int idx = tid - 32, u = idx / 3, i2 = idx % 3;
            float aA = 0.0f, aB = 0.0f;
            for (int h2 = 0; h2 < 32; ++h2) {
                const float* wr = &wout[h2 * TW];
                const float* mr = &Mlds[h2 * TC];
#pragma unroll
                for (int v = 0; v < 16; ++v) aA += wr[576 + u * 16 + v] * mr[24 + v * 3 + i2];
#pragma unroll
                for (int v = 0; v < 8; ++v)
                    aB += wr[704 + u * 8 + v] * mr[72 + v * 3 + i2]
                        + wr[768 + u * 8 + v] * mr[96 + v * 3 + i2]
                        + wr[832 + u * 8 + v] * mr[120 + v * 3 + i2];
            }
            o1v = (aA * 0.125f + aB * i32) * i32;
        }
        __syncthreads();
        if (tid < 16) {
            o0[(z * NN + a) * 16 + tid] = relu_r(outS[tid]) * s;
        } else if (tid >= 32 && tid < 56) {
            int idx = tid - 32, u = idx / 3, i2 = idx % 3;
            float g = sigmoid_r(outS[16 + u]);
            o1[((z * NN + a) * 8 + u) * 3 + i2] = o1v * g * s;
        }
    } else {
        if (tid < 2) {
            float aA = 0.0f, aB = 0.0f;
            for (int h2 = 0; h2 < 32; ++h2) {
                const float* wr = &wout[h2 * TW];
                const float* mr = &Mlds[h2 * TC];
#pragma unroll
                for (int v = 0; v < 16; ++v) aA += wr[tid * 16 + v] * mr[v];
#pragma unroll
                for (int v = 0; v < 8; ++v) aB += wr[32 + tid * 8 + v] * mr[16 + v];
            }
            o0[(z * NN + a) * 8 + tid * 4] = (aA * i32 + aB * 0.25f) * i32;
        } else if (tid >= 32 && tid < 38) {
            int idx = tid - 32, u = idx / 3, i2 = idx % 3;
            float aA = 0.0f, aB = 0.0f;
            for (int h2 = 0; h2 < 32; ++h2) {
                const float* wr = &wout[h2 * TW];
                const float* mr = &Mlds[h2 * TC];
#pragma unroll
                for (int v = 0; v < 16; ++v) aA += wr[48 + u * 16 + v] * mr[24 + v * 3 + i2];
#pragma unroll
                for (int v = 0; v < 8; ++v)
                    aB += wr[80 + u * 8 + v] * mr[72 + v * 3 + i2]
                        + wr[96 + u * 8 + v] * mr[96 + v * 3 + i2]
                        + wr[112 + u * 8 + v] * mr[120 + v * 3 + i2];
            }
            o0[(z * NN + a) * 8 + u * 4 + 1 + i2] = (aA * 0.125f + aB * i32) * i32;
        }
    }
}

extern "C" void kernel_launch(void* const* d_in, const int* in_sizes, int n_in,
                              void* d_out, int out_size, void* d_ws, size_t ws_size,
                              hipStream_t stream) {
    const float* features = (const float*)d_in[0];
    const float* geometry = (const float*)d_in[1];
    const float* c0w0   = (const float*)d_in[2];
    const float* c0b0   = (const float*)d_in[3];
    const float* c0wout = (const float*)d_in[4];
    const float* c1w0   = (const float*)d_in[5];
    const float* c1b0   = (const float*)d_in[6];
    const float* c1wout = (const float*)d_in[7];
    const float* c2w0   = (const float*)d_in[8];
    const float* c2b0   = (const float*)d_in[9];
    const float* c2wout = (const float*)d_in[10];
    float* out = (float*)d_out;

    float* ws  = (float*)d_ws;
    float* f0a = ws;                  // [B*N*16]
    float* f1a = f0a + BB * NN * 16;  // [B*N*8*3]
    float* f0b = f1a + BB * NN * 24;
    float* f1b = f0b + BB * NN * 16;

    const size_t NPAIR = (size_t)BB * NN * NN;
    const size_t fEnd  = (size_t)(BB * NN * 16) * 2 + (size_t)(BB * NN * 24) * 2;  // 30720
    const size_t need  = fEnd + NPAIR * 8 + 3 * NPAIR * 32 +
                         (size_t)BB * NN * SPLIT * 32 * 144;  // floats

    if (ws_size >= need * sizeof(float)) {
        float* Yg   = ws + fEnd;
        float* h0   = Yg + NPAIR * 8;
        float* h1   = h0 + NPAIR * 32;
        float* h2   = h1 + NPAIR * 32;
        float* part = h2 + NPAIR * 32;

        dim3 blk(256);
        hipLaunchKernelGGL(tfn_pre, dim3((unsigned)(NPAIR * 32 / 256)), blk, 0, stream,
                           geometry, c0w0, c0b0, c1w0, c1b0, c2w0, c2b0, Yg, h0, h1, h2);

        dim3 g1(BB * NN * SPLIT), g2(BB * NN);
        hipLaunchKernelGGL((tfn_stage1<0>), g1, blk, 0, stream, features, nullptr, Yg, h0, part);
        hipLaunchKernelGGL((tfn_stage2<0>), g2, blk, 0, stream, part, c0wout, f0a, f1a);
        hipLaunchKernelGGL((tfn_stage1<1>), g1, blk, 0, stream, f0a, f1a, Yg, h1, part);
        hipLaunchKernelGGL((tfn_stage2<1>), g2, blk, 0, stream, part, c1wout, f0b, f1b);
        hipLaunchKernelGGL((tfn_stage1<2>), g1, blk, 0, stream, f0b, f1b, Yg, h2, part);
        hipLaunchKernelGGL((tfn_stage2<2>), g2, blk, 0, stream, part, c2wout, out, nullptr);
    } else {
        dim3 grid(BB * NN), blk(256);
        hipLaunchKernelGGL((tfn_layer_mono<0>), grid, blk, 0, stream,
                           geometry, features, nullptr, c0w0, c0b0, c0wout, f0a, f1a);
        hipLaunchKernelGGL((tfn_layer_mono<1>), grid, blk, 0, stream,
                           geometry, f0a, f1a, c1w0, c1b0, c1wout, f0b, f1b);
        hipLaunchKernelGGL((tfn_layer_mono<2>), grid, blk, 0, stream,
                           geometry, f0b, f1b, c2w0, c2b0, c2wout, out, nullptr);
    }
}

// Round 3
// 184.419 us; speedup vs baseline: 1.5338x; 1.5338x over previous
//
#include <hip/hip_runtime.h>
#include <math.h>

// Tensor-field-network decoder: B=2, N=192, 3 conv layers (2 gated + 1 final).
// Round-3 structure: 3 fused split-K conv kernels + 1 tiny sum kernel.
//   tfn_s1<L>: grid = B*N*SPLIT. Each block: 48 neighbors of one atom.
//     - load phase: sum previous layer's 4 partials + apply relu/sigmoid/gate
//       (L0: load features); stage geometry slice in LDS.
//     - 3 chunks x {compute basis/Y from LDS geo; radial h; T-columns;
//       rank-16 M update} -- NO global traffic inside the loop.
//     - in-block epilogue: contract partial M[32][TC] with wout (linear!) and
//       emit 48 (8 for L2) pre-activation floats. Kills the 28MB partial-M
//       round trip of round 2.
//   tfn_fin: sums 4 partials of the last layer -> out.
// Fallback to verified round-1 monolithic kernels if ws is too small.

#define NN 192
#define BB 2
#define SPLIT 4
#define NS 48            // neighbors per block
#define NBASIS 10
#define HHID 32

__device__ __forceinline__ float relu_r(float x) {
    return fmaxf(x, 0.0f) * 1.4142135623730951f;
}
__device__ __forceinline__ float sigmoid_r(float x) {
    return (1.0f / (1.0f + expf(-x))) * 1.84623f;
}

#define S_SCALE 0.07216878364870323f   // 1/sqrt(192)
#define ISQ10   0.31622776601683794f   // 1/sqrt(10)
#define I32     0.1767766952966369f    // 1/sqrt(32)

// ---------------------------------------------------------------------------
// Fused split-K conv layer.
//   fin:  L0: features [B,N,16]; L1/L2: prev part [B*N*SPLIT, 48]
//   part: out partials [B*N*SPLIT, NOUT]
// ---------------------------------------------------------------------------
template <int LAYER>
__global__ __launch_bounds__(256, 4) void tfn_s1(
    const float* __restrict__ fin,
    const float* __restrict__ geo,
    const float* __restrict__ w0,
    const float* __restrict__ b0g,
    const float* __restrict__ wout,
    float* __restrict__ part)
{
    constexpr int TC   = (LAYER == 0) ? 64 : 144;
    constexpr int TW   = (LAYER == 0) ? 512 : (LAYER == 1 ? 896 : 128);
    constexpr int CPT  = TC / 8;    // M cols per thread
    constexpr int CPTT = TC / 16;   // T cols per thread
    constexpr int NOUT = (LAYER == 2) ? 8 : 48;
    constexpr int MSTR = TC + 1;    // padded M row stride (bank spread)

    // ---- shared memory layout (floats) ----
    constexpr int oGeo = 0;                               // 148 (48*3 + own atom + pad)
    constexpr int oW0  = oGeo + 148;                      // 320
    constexpr int oB0  = oW0 + 320;                       // 32
    constexpr int oF0  = oB0 + 32;                        // 768
    constexpr int oF1  = oF0 + 768;                       // 1152 (L!=0)
    constexpr int oBas = oF1 + ((LAYER == 0) ? 0 : 1152); // 160
    constexpr int oY   = oBas + 160;                      // 128
    constexpr int oH   = oY + 128;                        // 512
    constexpr int oT   = oH + 512;                        // 16*TC (>= 48*48 for L1/L2 raw sums)
    constexpr int chunkEnd = oT + 16 * TC;
    constexpr int oM = 0;                                 // 32*MSTR (aliases everything above)
    constexpr int oU = 32 * MSTR;                         // NOUT*33
    constexpr int epiEnd = oU + NOUT * 33;
    constexpr int SM = (chunkEnd > epiEnd) ? chunkEnd : epiEnd;
    __shared__ float sm[SM];

    const int tid  = threadIdx.x;
    const int blk  = blockIdx.x;
    const int sp   = blk & (SPLIT - 1);
    const int atom = blk >> 2;          // z*NN + a
    const int z    = atom / NN, a = atom % NN;
    const int nb0  = sp * NS;

    // ---- stage geometry slice + own atom + radial weights ----
    for (int i = tid; i < NS * 3; i += 256) sm[oGeo + i] = geo[(z * NN + nb0) * 3 + i];
    if (tid < 3) sm[oGeo + 144 + tid] = geo[(z * NN + a) * 3 + tid];
    for (int i = tid; i < NBASIS * HHID; i += 256) sm[oW0 + i] = w0[i];
    if (tid < HHID) sm[oB0 + tid] = b0g[tid];

    // ---- load/activate input features for the 48 neighbors ----
    if constexpr (LAYER == 0) {
        for (int i = tid; i < NS * 16; i += 256)
            sm[oF0 + i] = fin[(z * NN + nb0) * 16 + i] * S_SCALE;
        __syncthreads();
    } else {
        // phase L-A: raw sums of 4 split partials -> sm[oT + loc*48 + c]
        for (int rep = 0; rep < 9; ++rep) {
            int idx = rep * 256 + tid;
            int loc = idx / 48, c = idx - loc * 48;
            int pb = ((z * NN + nb0 + loc) * SPLIT) * 48 + c;
            sm[oT + idx] = fin[pb] + fin[pb + 48] + fin[pb + 96] + fin[pb + 144];
        }
        __syncthreads();
        // phase L-B: activations + gating -> f0S / f1S
        for (int rep = 0; rep < 8; ++rep) {
            int idx = rep * 256 + tid;
            if (idx < NS * 40) {
                int loc = idx / 40, c2 = idx - loc * 40;
                const float* cs = &sm[oT + loc * 48];
                if (c2 < 16) {
                    sm[oF0 + loc * 16 + c2] = relu_r(cs[c2]) * S_SCALE;
                } else {
                    int j = c2 - 16, u = j / 3, i2 = j - u * 3;
                    sm[oF1 + (loc * 8 + u) * 3 + i2] =
                        cs[24 + j] * sigmoid_r(cs[16 + u]) * S_SCALE;
                }
            }
        }
        __syncthreads();
    }

    float Macc[CPT];
#pragma unroll
    for (int j = 0; j < CPT; ++j) Macc[j] = 0.0f;
    const int hh  = tid >> 3;
    const int cg0 = (tid & 7) * CPT;

    // ---- 3 chunks of 16 neighbors ----
    for (int cb = 0; cb < NS / 16; ++cb) {
        // phase A: basis + spherical harmonics (from LDS geometry)
        {
            const int bl = tid & 15, item = tid >> 4;
            if (item < 12) {
                const int loc = cb * 16 + bl;
                float rx = sm[oGeo + 144] - sm[oGeo + loc * 3 + 0];
                float ry = sm[oGeo + 145] - sm[oGeo + loc * 3 + 1];
                float rz = sm[oGeo + 146] - sm[oGeo + loc * 3 + 2];
                float r = sqrtf(rx * rx + ry * ry + rz * rz + 1e-12f);
                if (item < NBASIS) {
                    float dg = r * 2.25f - (float)item;   // step = 4/9
                    float bas = 0.0f;
                    if (fabsf(dg) < 1.0f) {
                        float cc = cosf(1.5707963267948966f * dg);
                        bas = cc * cc;
                    }
                    sm[oBas + bl * NBASIS + item] = bas;
                } else {
                    float inv = 1.0f / fmaxf(r, 1e-6f);
                    float ux = rx * inv, uy = ry * inv, uz = rz * inv;
                    if (item == 10) {
                        sm[oY + bl * 8 + 0] = 0.4886025119029199f * uy;
                        sm[oY + bl * 8 + 1] = 0.4886025119029199f * uz;
                        sm[oY + bl * 8 + 2] = 0.4886025119029199f * ux;
                    } else {
                        sm[oY + bl * 8 + 3] = 1.0925484305920792f * ux * uy;
                        sm[oY + bl * 8 + 4] = 1.0925484305920792f * uy * uz;
                        sm[oY + bl * 8 + 5] = 0.31539156525252005f * (2.0f * uz * uz - ux * ux - uy * uy);
                        sm[oY + bl * 8 + 6] = 1.0925484305920792f * ux * uz;
                        sm[oY + bl * 8 + 7] = 0.5462742152960396f * (ux * ux - uy * uy);
                    }
                }
            }
        }
        __syncthreads();

        // phase B: radial hidden h (16x32) + T columns (16xTC)
#pragma unroll
        for (int rep = 0; rep < 2; ++rep) {
            int idx = rep * 256 + tid;
            int bl = idx >> 5, j = idx & 31;
            float su = 0.0f;
#pragma unroll
            for (int k = 0; k < NBASIS; ++k)
                su += sm[oBas + bl * NBASIS + k] * sm[oW0 + k * HHID + j];
            sm[oH + bl * HHID + j] = relu_r(su * ISQ10 + sm[oB0 + j]);
        }
        {
            const int bl = tid >> 4, cg = tid & 15;
            const int loc = cb * 16 + bl;
            const float* Yb = &sm[oY + bl * 8];
#pragma unroll
            for (int jj = 0; jj < CPTT; ++jj) {
                int c = cg * CPTT + jj;
                float val;
                if constexpr (LAYER == 0) {
                    if (c < 16) {
                        val = 0.28209479177387814f * sm[oF0 + loc * 16 + c];       // (0,0,0)
                    } else {
                        int q = c - 16, v = q / 3, i2 = q - v * 3;                 // (1,0,1)
                        val = Yb[i2] * sm[oF0 + loc * 16 + v] * 0.5773502691896258f;
                    }
                } else {
                    if (c < 16) {
                        val = 0.28209479177387814f * sm[oF0 + loc * 16 + c];       // (0,0,0)
                    } else if (c < 24) {
                        int v = c - 16;                                            // (0,1,1)
                        const float* f = &sm[oF1 + (loc * 8 + v) * 3];
                        val = (f[0] * Yb[0] + f[1] * Yb[1] + f[2] * Yb[2]) * 0.5773502691896258f;
                    } else if (c < 72) {
                        int q = c - 24, v = q / 3, i2 = q - v * 3;                 // (1,0,1)
                        val = Yb[i2] * sm[oF0 + loc * 16 + v] * 0.5773502691896258f;
                    } else if (c < 96) {
                        int q = c - 72, v = q / 3, i2 = q - v * 3;                 // (1,1,0)
                        val = sm[oF1 + (loc * 8 + v) * 3 + i2] * (0.28209479177387814f * 0.5773502691896258f);
                    } else if (c < 120) {
                        int q = c - 96, v = q / 3, i2 = q - v * 3;                 // (1,1,1)
                        const float* f = &sm[oF1 + (loc * 8 + v) * 3];
                        int i1 = (i2 + 1) % 3, i3 = (i2 + 2) % 3;
                        val = (f[i1] * Yb[i3] - f[i3] * Yb[i1]) * 0.4082482904638631f;
                    } else {
                        int q = c - 120, v = q / 3, i2 = q - v * 3;                // (1,1,2)
                        const float* f = &sm[oF1 + (loc * 8 + v) * 3];
                        const float D  = 0.31622776601683794f;
                        const float Bc = 0.18257418583505536f;
                        float Y20 = Yb[3], Y21 = Yb[4], Y22 = Yb[5], Y23 = Yb[6], Y24 = Yb[7];
                        if (i2 == 0)      val = D * (Y20 * f[2] + Y21 * f[1]) - (Bc * Y22 + D * Y24) * f[0];
                        else if (i2 == 1) val = D * (Y21 * f[0] + Y23 * f[2]) + 2.0f * Bc * Y22 * f[1];
                        else              val = D * (Y20 * f[0] + Y23 * f[1] + Y24 * f[2]) - Bc * Y22 * f[2];
                    }
                }
                sm[oT + bl * TC + c] = val;
            }
        }
        __syncthreads();

        // phase C: rank-16 M update
#pragma unroll 4
        for (int bl = 0; bl < 16; ++bl) {
            float hv = sm[oH + bl * HHID + hh];
#pragma unroll
            for (int j = 0; j < CPT; ++j) Macc[j] += hv * sm[oT + bl * TC + cg0 + j];
        }
        __syncthreads();
    }

    // ---- epilogue: M -> LDS (aliased over dead buffers), contract with wout ----
#pragma unroll
    for (int j = 0; j < CPT; ++j) sm[oM + hh * MSTR + cg0 + j] = Macc[j];
    __syncthreads();

    constexpr int NITEM = NOUT * 32;
    for (int rep = 0; rep < NITEM / 256; ++rep) {
        int idx = rep * 256 + tid;
        int h = idx / NOUT, o = idx - h * NOUT;   // consecutive lanes -> same wout row
        const float* wr = &wout[h * TW];
        const float* mr = &sm[oM + h * MSTR];
        float U;
        if constexpr (LAYER == 0) {
            const float sc = I32 * 0.25f;
            float acc = 0.0f;
            if (o < 24) {
#pragma unroll
                for (int v = 0; v < 16; ++v) acc += wr[o * 16 + v] * mr[v];
            } else {
                int j = o - 24, u = j / 3, i2 = j - u * 3;
#pragma unroll
                for (int v = 0; v < 16; ++v) acc += wr[384 + u * 16 + v] * mr[16 + v * 3 + i2];
            }
            U = acc * sc;
        } else if constexpr (LAYER == 1) {
            float aA = 0.0f, aB = 0.0f;
            if (o < 24) {
#pragma unroll
                for (int v = 0; v < 16; ++v) aA += wr[o * 16 + v] * mr[v];
#pragma unroll
                for (int v = 0; v < 8; ++v) aB += wr[384 + o * 8 + v] * mr[16 + v];
                U = (aA * I32 + aB * 0.25f) * I32;
            } else {
                int j = o - 24, u = j / 3, i2 = j - u * 3;
#pragma unroll
                for (int v = 0; v < 16; ++v) aA += wr[576 + u * 16 + v] * mr[24 + v * 3 + i2];
#pragma unroll
                for (int v = 0; v < 8; ++v)
                    aB += wr[704 + u * 8 + v] * mr[72 + v * 3 + i2]
                        + wr[768 + u * 8 + v] * mr[96 + v * 3 + i2]
                        + wr[832 + u * 8 + v] * mr[120 + v * 3 + i2];
                U = (aA * 0.125f + aB * I32) * I32;
            }
        } else {  // LAYER == 2
            float aA = 0.0f, aB = 0.0f;
            if (o < 2) {
#pragma unroll
                for (int v = 0; v < 16; ++v) aA += wr[o * 16 + v] * mr[v];
#pragma unroll
                for (int v = 0; v < 8; ++v) aB += wr[32 + o * 8 + v] * mr[16 + v];
                U = (aA * I32 + aB * 0.25f) * I32;
            } else {
                int j = o - 2, u = j / 3, i2 = j - u * 3;
#pragma unroll
                for (int v = 0; v < 16; ++v) aA += wr[48 + u * 16 + v] * mr[24 + v * 3 + i2];
#pragma unroll
                for (int v = 0; v < 8; ++v)
                    aB += wr[80 + u * 8 + v] * mr[72 + v * 3 + i2]
                        + wr[96 + u * 8 + v] * mr[96 + v * 3 + i2]
                        + wr[112 + u * 8 + v] * mr[120 + v * 3 + i2];
                U = (aA * 0.125f + aB * I32) * I32;
            }
        }
        sm[oU + o * 33 + h] = U;
    }
    __syncthreads();

    if (tid < NOUT) {
        float su = 0.0f;
#pragma unroll
        for (int h = 0; h < 32; ++h) su += sm[oU + tid * 33 + h];
        part[blk * NOUT + tid] = su;
    }
}

// ---------------------------------------------------------------------------
// Final sum: out[atom][2*4] interleaved from 4 split partials of layer 2.
// ---------------------------------------------------------------------------
__global__ __launch_bounds__(256) void tfn_fin(
    const float* __restrict__ part2, float* __restrict__ out)
{
    int t = blockIdx.x * 256 + threadIdx.x;  // < BB*NN*8
    int atom = t >> 3, o = t & 7;
    const float* p = &part2[atom * SPLIT * 8];
    float su = p[o] + p[8 + o] + p[16 + o] + p[24 + o];
    int pos;
    if (o < 2) pos = o * 4;
    else { int j = o - 2; pos = (j / 3) * 4 + 1 + (j - (j / 3) * 3); }
    out[atom * 8 + pos] = su;
}

// ---------------------------------------------------------------------------
// Fallback: verified round-1 monolithic kernel (used only if ws too small).
// ---------------------------------------------------------------------------
template <int LAYER>
__global__ __launch_bounds__(256) void tfn_layer_mono(
    const float* __restrict__ geo,
    const float* __restrict__ fin0,
    const float* __restrict__ fin1,
    const float* __restrict__ w0,
    const float* __restrict__ b0g,
    const float* __restrict__ wout,
    float* __restrict__ o0,
    float* __restrict__ o1)
{
    constexpr int TC   = (LAYER == 0) ? 64 : 144;
    constexpr int TW   = (LAYER == 0) ? 512 : (LAYER == 1 ? 896 : 128);
    constexpr int CPT  = TC / 8;
    constexpr int CPTT = TC / 16;

    const int tid = threadIdx.x;
    const int blk = blockIdx.x;
    const int z = blk / NN, a = blk % NN;

    __shared__ float geoL[NN * 3];
    __shared__ float f0L[NN * 16];
    __shared__ float f1L[(LAYER == 0) ? 1 : (NN * 24)];
    __shared__ float w0L[NBASIS * HHID];
    __shared__ float b0L[HHID];
    __shared__ float YC[16 * 8];
    __shared__ float basC[16 * NBASIS];
    __shared__ float hC[16 * HHID];
    __shared__ float tC[16 * TC];
    __shared__ float Mlds[HHID * TC];
    __shared__ float outS[32];

    const float s = S_SCALE;

    for (int i = tid; i < NN * 3; i += 256) geoL[i] = geo[z * NN * 3 + i];
    for (int i = tid; i < NN * 16; i += 256) {
        float v = fin0[z * NN * 16 + i];
        if (LAYER == 0) v *= s;
        f0L[i] = v;
    }
    if constexpr (LAYER != 0) {
        for (int i = tid; i < NN * 24; i += 256) f1L[i] = fin1[z * NN * 24 + i];
    }
    for (int i = tid; i < NBASIS * HHID; i += 256) w0L[i] = w0[i];
    if (tid < HHID) b0L[tid] = b0g[tid];
    __syncthreads();

    const float ax = geoL[a * 3 + 0], ay = geoL[a * 3 + 1], az = geoL[a * 3 + 2];

    float Macc[CPT];
#pragma unroll
    for (int j = 0; j < CPT; ++j) Macc[j] = 0.0f;
    const int hh  = tid >> 3;
    const int cg0 = (tid & 7) * CPT;

    for (int cb = 0; cb < NN / 16; ++cb) {
        {
            const int bl = tid & 15, item = tid >> 4;
            const int b = cb * 16 + bl;
            float rx = ax - geoL[b * 3 + 0];
            float ry = ay - geoL[b * 3 + 1];
            float rz = az - geoL[b * 3 + 2];
            float r = sqrtf(rx * rx + ry * ry + rz * rz + 1e-12f);
            float inv = 1.0f / fmaxf(r, 1e-6f);
            float ux = rx * inv, uy = ry * inv, uz = rz * inv;
            if (item < NBASIS) {
                float dg = r * 2.25f - (float)item;
                float bas = 0.0f;
                if (fabsf(dg) < 1.0f) {
                    float cc = cosf(1.5707963267948966f * dg);
                    bas = cc * cc;
                }
                basC[bl * NBASIS + item] = bas;
            } else if (item == 10) {
                YC[bl * 8 + 0] = 0.4886025119029199f * uy;
                YC[bl * 8 + 1] = 0.4886025119029199f * uz;
                YC[bl * 8 + 2] = 0.4886025119029199f * ux;
            } else if (item == 11) {
                YC[bl * 8 + 3] = 1.0925484305920792f * ux * uy;
                YC[bl * 8 + 4] = 1.0925484305920792f * uy * uz;
                YC[bl * 8 + 5] = 0.31539156525252005f * (2.0f * uz * uz - ux * ux - uy * uy);
                YC[bl * 8 + 6] = 1.0925484305920792f * ux * uz;
                YC[bl * 8 + 7] = 0.5462742152960396f * (ux * ux - uy * uy);
            }
        }
        __syncthreads();

#pragma unroll
        for (int rep = 0; rep < 2; ++rep) {
            int idx = tid + rep * 256;
            int bl = idx >> 5, h2 = idx & 31;
            float su = 0.0f;
#pragma unroll
            for (int k = 0; k < NBASIS; ++k) su += basC[bl * NBASIS + k] * w0L[k * HHID + h2];
            hC[bl * HHID + h2] = relu_r(su * ISQ10 + b0L[h2]);
        }

        {
            const int bl = tid >> 4, cg = tid & 15;
            const int b = cb * 16 + bl;
            const float* Yb = &YC[bl * 8];
#pragma unroll
            for (int jj = 0; jj < CPTT; ++jj) {
                int c = cg * CPTT + jj;
                float val;
                if constexpr (LAYER == 0) {
                    if (c < 16) {
                        val = 0.28209479177387814f * f0L[b * 16 + c];
                    } else {
                        int q = c - 16, v = q / 3, i2 = q % 3;
                        val = Yb[i2] * f0L[b * 16 + v] * 0.5773502691896258f;
                    }
                } else {
                    if (c < 16) {
                        val = 0.28209479177387814f * f0L[b * 16 + c];
                    } else if (c < 24) {
                        int v = c - 16;
                        const float* f = &f1L[(b * 8 + v) * 3];
                        val = (f[0] * Yb[0] + f[1] * Yb[1] + f[2] * Yb[2]) * 0.5773502691896258f;
                    } else if (c < 72) {
                        int q = c - 24, v = q / 3, i2 = q % 3;
                        val = Yb[i2] * f0L[b * 16 + v] * 0.5773502691896258f;
                    } else if (c < 96) {
                        int q = c - 72, v = q / 3, i2 = q % 3;
                        val = f1L[(b * 8 + v) * 3 + i2] * (0.28209479177387814f * 0.5773502691896258f);
                    } else if (c < 120) {
                        int q = c - 96, v = q / 3, i2 = q % 3;
                        const float* f = &f1L[(b * 8 + v) * 3];
                        int i1 = (i2 + 1) % 3, i3 = (i2 + 2) % 3;
                        val = (f[i1] * Yb[i3] - f[i3] * Yb[i1]) * 0.4082482904638631f;
                    } else {
                        int q = c - 120, v = q / 3, i2 = q % 3;
                        const float* f = &f1L[(b * 8 + v) * 3];
                        const float D = 0.31622776601683794f;
                        const float Bc = 0.18257418583505536f;
                        float Y20 = Yb[3], Y21 = Yb[4], Y22 = Yb[5], Y23 = Yb[6], Y24 = Yb[7];
                        if (i2 == 0)      val = D * (Y20 * f[2] + Y21 * f[1]) - (Bc * Y22 + D * Y24) * f[0];
                        else if (i2 == 1) val = D * (Y21 * f[0] + Y23 * f[2]) + 2.0f * Bc * Y22 * f[1];
                        else              val = D * (Y20 * f[0] + Y23 * f[1] + Y24 * f[2]) - Bc * Y22 * f[2];
                    }
                }
                tC[bl * TC + c] = val;
            }
        }
        __syncthreads();

#pragma unroll 4
        for (int bl = 0; bl < 16; ++bl) {
            float hv = hC[bl * HHID + hh];
#pragma unroll
            for (int j = 0; j < CPT; ++j) Macc[j] += hv * tC[bl * TC + cg0 + j];
        }
        __syncthreads();
    }

#pragma unroll
    for (int j = 0; j < CPT; ++j) Mlds[hh * TC + cg0 + j] = Macc[j];
    __syncthreads();

    const float i32 = I32;

    if constexpr (LAYER == 0) {
        const float sc = i32 * 0.25f;
        float o1v = 0.0f;
        if (tid < 24) {
            float acc = 0.0f;
            for (int h2 = 0; h2 < 32; ++h2) {
                const float* wr = &wout[h2 * TW + tid * 16];
                const float* mr = &Mlds[h2 * TC];
#pragma unroll
                for (int v = 0; v < 16; ++v) acc += wr[v] * mr[v];
            }
            outS[tid] = acc * sc;
        } else if (tid >= 32 && tid < 56) {
            int idx = tid - 32, u = idx / 3, i2 = idx % 3;
            float acc = 0.0f;
            for (int h2 = 0; h2 < 32; ++h2) {
                const float* wr = &wout[h2 * TW + 384 + u * 16];
                const float* mr = &Mlds[h2 * TC + 16 + i2];
#pragma unroll
                for (int v = 0; v < 16; ++v) acc += wr[v] * mr[v * 3];
            }
            o1v = acc * sc;
        }
        __syncthreads();
        if (tid < 16) {
            o0[(z * NN + a) * 16 + tid] = relu_r(outS[tid]) * s;
        } else if (tid >= 32 && tid < 56) {
            int idx = tid - 32, u = idx / 3, i2 = idx % 3;
            float g = sigmoid_r(outS[16 + u]);
            o1[((z * NN + a) * 8 + u) * 3 + i2] = o1v * g * s;
        }
    } else if constexpr (LAYER == 1) {
        float o1v = 0.0f;
        if (tid < 24) {
            float aA = 0.0f, aB = 0.0f;
            for (int h2 = 0; h2 < 32; ++h2) {
                const float* wr = &wout[h2 * TW];
                const float* mr = &Mlds[h2 * TC];
#pragma unroll
                for (int v = 0; v < 16; ++v) aA += wr[tid * 16 + v] * mr[v];
#pragma unroll
                for (int v = 0; v < 8; ++v) aB += wr[384 + tid * 8 + v] * mr[16 + v];
            }
            outS[tid] = (aA * i32 + aB * 0.25f) * i32;
        } else if (tid >= 32 && tid < 56) {
            int idx = tid - 32, u = idx / 3, i2 = idx % 3;
            float aA = 0.0f, aB = 0.0f;
            for (int h2 = 0; h2 < 32; ++h2) {
                const float* wr = &wout[h2 * TW];
                const float* mr = &Mlds[h2 * TC];
#pragma unroll
                for (int v = 0; v < 16; ++v) aA += wr[576 + u * 16 + v] * mr[24 + v * 3 + i2];
#pragma unroll
                for (int v = 0; v < 8; ++v)
                    aB += wr[704 + u * 8 + v] * mr[72 + v * 3 + i2]
                        + wr[768 + u * 8 + v] * mr[96 + v * 3 + i2]
                        + wr[832 + u * 8 + v] * mr[120 + v * 3 + i2];
            }
            o1v = (aA * 0.125f + aB * i32) * i32;
        }
        __syncthreads();
        if (tid < 16) {
            o0[(z * NN + a) * 16 + tid] = relu_r(outS[tid]) * s;
        } else if (tid >= 32 && tid < 56) {
            int idx = tid - 32, u = idx / 3, i2 = idx % 3;
            float g = sigmoid_r(outS[16 + u]);
            o1[((z * NN + a) * 8 + u) * 3 + i2] = o1v * g * s;
        }
    } else {
        if (tid < 2) {
            float aA = 0.0f, aB = 0.0f;
            for (int h2 = 0; h2 < 32; ++h2) {
                const float* wr = &wout[h2 * TW];
                const float* mr = &Mlds[h2 * TC];
#pragma unroll
                for (int v = 0; v < 16; ++v) aA += wr[tid * 16 + v] * mr[v];
#pragma unroll
                for (int v = 0; v < 8; ++v) aB += wr[32 + tid * 8 + v] * mr[16 + v];
            }
            o0[(z * NN + a) * 8 + tid * 4] = (aA * i32 + aB * 0.25f) * i32;
        } else if (tid >= 32 && tid < 38) {
            int idx = tid - 32, u = idx / 3, i2 = idx % 3;
            float aA = 0.0f, aB = 0.0f;
            for (int h2 = 0; h2 < 32; ++h2) {
                const float* wr = &wout[h2 * TW];
                const float* mr = &Mlds[h2 * TC];
#pragma unroll
                for (int v = 0; v < 16; ++v) aA += wr[48 + u * 16 + v] * mr[24 + v * 3 + i2];
#pragma unroll
                for (int v = 0; v < 8; ++v)
                    aB += wr[80 + u * 8 + v] * mr[72 + v * 3 + i2]
                        + wr[96 + u * 8 + v] * mr[96 + v * 3 + i2]
                        + wr[112 + u * 8 + v] * mr[120 + v * 3 + i2];
            }
            o0[(z * NN + a) * 8 + u * 4 + 1 + i2] = (aA * 0.125f + aB * i32) * i32;
        }
    }
}

extern "C" void kernel_launch(void* const* d_in, const int* in_sizes, int n_in,
                              void* d_out, int out_size, void* d_ws, size_t ws_size,
                              hipStream_t stream) {
    const float* features = (const float*)d_in[0];
    const float* geometry = (const float*)d_in[1];
    const float* c0w0   = (const float*)d_in[2];
    const float* c0b0   = (const float*)d_in[3];
    const float* c0wout = (const float*)d_in[4];
    const float* c1w0   = (const float*)d_in[5];
    const float* c1b0   = (const float*)d_in[6];
    const float* c1wout = (const float*)d_in[7];
    const float* c2w0   = (const float*)d_in[8];
    const float* c2b0   = (const float*)d_in[9];
    const float* c2wout = (const float*)d_in[10];
    float* out = (float*)d_out;

    float* ws = (float*)d_ws;
    const size_t NBLK = (size_t)BB * NN * SPLIT;                 // 1536
    const size_t need = NBLK * 48 * 2 + NBLK * 8;                // partA, partB, part2

    if (ws_size >= need * sizeof(float)) {
        float* partA = ws;
        float* partB = partA + NBLK * 48;
        float* part2 = partB + NBLK * 48;

        dim3 g1((unsigned)NBLK), blk(256);
        hipLaunchKernelGGL((tfn_s1<0>), g1, blk, 0, stream,
                           features, geometry, c0w0, c0b0, c0wout, partA);
        hipLaunchKernelGGL((tfn_s1<1>), g1, blk, 0, stream,
                           partA, geometry, c1w0, c1b0, c1wout, partB);
        hipLaunchKernelGGL((tfn_s1<2>), g1, blk, 0, stream,
                           partB, geometry, c2w0, c2b0, c2wout, part2);
        hipLaunchKernelGGL(tfn_fin, dim3(BB * NN * 8 / 256), blk, 0, stream,
                           part2, out);
    } else {
        float* f0a = ws;
        float* f1a = f0a + BB * NN * 16;
        float* f0b = f1a + BB * NN * 24;
        float* f1b = f0b + BB * NN * 16;
        dim3 grid(BB * NN), blk(256);
        hipLaunchKernelGGL((tfn_layer_mono<0>), grid, blk, 0, stream,
                           geometry, features, nullptr, c0w0, c0b0, c0wout, f0a, f1a);
        hipLaunchKernelGGL((tfn_layer_mono<1>), grid, blk, 0, stream,
                           geometry, f0a, f1a, c1w0, c1b0, c1wout, f0b, f1b);
        hipLaunchKernelGGL((tfn_layer_mono<2>), grid, blk, 0, stream,
                           geometry, f0b, f1b, c2w0, c2b0, c2wout, out, nullptr);
    }
}

// Round 4
// 144.513 us; speedup vs baseline: 1.9574x; 1.2761x over previous
//
#include <hip/hip_runtime.h>
#include <math.h>

// Tensor-field-network decoder: B=2, N=192, 3 conv layers (2 gated + 1 final).
// Round-4: flattened single-pass split-K blocks with register-tiled M update.
//   tfn_s1<L>: grid = B*N*SPLIT (1536 blocks, 256 thr).
//     P0: stage f (or sum+stash prev partials) + basis/Y for all 48 neighbors
//     P1: radial h (48x32) + activation/gating of prev-layer sums
//     P2: T columns for all 48 neighbors -> LDS (48 x TCP)
//     P3: M[32][TC] += h^T x T, register tile RxC per thread (L0 2x4, L1/2 4x5)
//     P4: epilogue: contract M with wout -> NOUT pre-activation partials
//   tfn_fin: sums 4 split partials of layer 2 -> out.
// 6 barriers/block (was 13); phase-C LDS bytes/FMA 4.2 -> 1.8.
// Fallback to verified round-1 monolithic kernels if ws too small.

#define NN 192
#define BB 2
#define SPLIT 4
#define NS 48
#define NBASIS 10
#define HHID 32

__device__ __forceinline__ float relu_r(float x) {
    return fmaxf(x, 0.0f) * 1.4142135623730951f;
}
__device__ __forceinline__ float sigmoid_r(float x) {
    return (1.0f / (1.0f + expf(-x))) * 1.84623f;
}

#define S_SCALE 0.07216878364870323f   // 1/sqrt(192)
#define ISQ10   0.31622776601683794f   // 1/sqrt(10)
#define I32     0.1767766952966369f    // 1/sqrt(32)

template <int LAYER>
__global__ __launch_bounds__(256, 4) void tfn_s1(
    const float* __restrict__ fin,   // L0: features [B,N,16]; L1/2: prev part [B*N*SPLIT,48]
    const float* __restrict__ geo,   // [B,N,3]
    const float* __restrict__ w0g,   // [10,32]
    const float* __restrict__ b0g,   // [32]
    const float* __restrict__ wout,  // [32, TW]
    float* __restrict__ part)        // [B*N*SPLIT, NOUT]
{
    constexpr int TC    = (LAYER == 0) ? 64 : 144;
    constexpr int TCP   = (LAYER == 0) ? 64 : 160;   // padded T stride
    constexpr int TW    = (LAYER == 0) ? 512 : (LAYER == 1 ? 896 : 128);
    constexpr int NOUT  = (LAYER == 2) ? 8 : 48;
    constexpr int MSTRE = TC + 1;                    // padded M stride (epilogue)
    constexpr int R     = (LAYER == 0) ? 2 : 4;      // h-rows per thread
    constexpr int C     = (LAYER == 0) ? 4 : 5;      // cols per thread

    // region A (offset 0) time-shares: prev-sums (2304) -> tC (48*TCP) -> Mlds+U
    constexpr int RA0 = 48 * TCP;
    constexpr int RAe = 32 * MSTRE + NOUT * 33;
    constexpr int RA  = (RA0 > RAe) ? RA0 : RAe;
    constexpr int oA   = 0;
    constexpr int oF0  = RA;                              // 48*16
    constexpr int oF1  = oF0 + 768;                       // 48*24 (L1/2)
    constexpr int oY   = oF1 + ((LAYER == 0) ? 0 : 1152); // 48*8
    constexpr int oBas = oY + 384;                        // 48*10
    constexpr int oH   = oBas + 480;                      // 48*32
    constexpr int SM   = oH + 1536;
    __shared__ float sm[SM];

    const int tid  = threadIdx.x;
    const int blk  = blockIdx.x;
    const int sp   = blk & (SPLIT - 1);
    const int atom = blk >> 2;           // z*NN + a
    const int z    = atom / NN, a = atom % NN;
    const int nb0  = sp * NS;

    // ---------------- P0: stage features / sum prev partials; basis + Y ----
    if constexpr (LAYER == 0) {
#pragma unroll
        for (int rp = 0; rp < 3; ++rp) {
            int i = rp * 256 + tid;
            sm[oF0 + i] = fin[(z * NN + nb0) * 16 + i] * S_SCALE;
        }
    } else {
#pragma unroll
        for (int rp = 0; rp < 9; ++rp) {
            int idx = rp * 256 + tid;                    // 48*48 = 2304
            int loc = idx / 48, c = idx - loc * 48;
            int pb = ((z * NN + nb0 + loc) * SPLIT) * 48 + c;
            sm[oA + idx] = fin[pb] + fin[pb + 48] + fin[pb + 96] + fin[pb + 144];
        }
    }
    {
        const float ax = geo[(z * NN + a) * 3 + 0];
        const float ay = geo[(z * NN + a) * 3 + 1];
        const float az = geo[(z * NN + a) * 3 + 2];
        for (int idx = tid; idx < 48 * 12; idx += 256) {
            int bl = idx / 12, it = idx - bl * 12;
            const float* gb = &geo[(z * NN + nb0 + bl) * 3];
            float rx = ax - gb[0], ry = ay - gb[1], rz = az - gb[2];
            float r = sqrtf(rx * rx + ry * ry + rz * rz + 1e-12f);
            if (it < NBASIS) {
                float dg = r * 2.25f - (float)it;        // step = 4/9
                float bas = 0.0f;
                if (fabsf(dg) < 1.0f) {
                    float cc = cosf(1.5707963267948966f * dg);
                    bas = cc * cc;
                }
                sm[oBas + bl * NBASIS + it] = bas;
            } else {
                float inv = 1.0f / fmaxf(r, 1e-6f);
                float ux = rx * inv, uy = ry * inv, uz = rz * inv;
                if (it == 10) {
                    sm[oY + bl * 8 + 0] = 0.4886025119029199f * uy;
                    sm[oY + bl * 8 + 1] = 0.4886025119029199f * uz;
                    sm[oY + bl * 8 + 2] = 0.4886025119029199f * ux;
                } else {
                    sm[oY + bl * 8 + 3] = 1.0925484305920792f * ux * uy;
                    sm[oY + bl * 8 + 4] = 1.0925484305920792f * uy * uz;
                    sm[oY + bl * 8 + 5] = 0.31539156525252005f * (2.0f * uz * uz - ux * ux - uy * uy);
                    sm[oY + bl * 8 + 6] = 1.0925484305920792f * ux * uz;
                    sm[oY + bl * 8 + 7] = 0.5462742152960396f * (ux * ux - uy * uy);
                }
            }
        }
    }
    __syncthreads();

    // ---------------- P1: radial hidden h; activate prev sums -> f0/f1 -----
#pragma unroll
    for (int rp = 0; rp < 6; ++rp) {
        int idx = rp * 256 + tid;                        // 48*32
        int bl = idx >> 5, j = idx & 31;
        float su = 0.0f;
#pragma unroll
        for (int k = 0; k < NBASIS; ++k)
            su += sm[oBas + bl * NBASIS + k] * w0g[k * HHID + j];
        sm[oH + idx] = relu_r(su * ISQ10 + b0g[j]);
    }
    if constexpr (LAYER != 0) {
        for (int rp = 0; rp < 8; ++rp) {
            int idx = rp * 256 + tid;                    // 48*40 = 1920
            if (idx < 1920) {
                int loc = idx / 40, c2 = idx - loc * 40;
                const float* cs = &sm[oA + loc * 48];
                if (c2 < 16) {
                    sm[oF0 + loc * 16 + c2] = relu_r(cs[c2]) * S_SCALE;
                } else {
                    int j = c2 - 16, u = j / 3, i2 = j - u * 3;
                    sm[oF1 + (loc * 8 + u) * 3 + i2] =
                        cs[24 + j] * sigmoid_r(cs[16 + u]) * S_SCALE;
                }
            }
        }
    }
    __syncthreads();

    // ---------------- P2: T columns for all 48 neighbors -------------------
    {
        constexpr int TITEMS = 48 * TC;
        for (int rp = 0; rp < TITEMS / 256; ++rp) {
            int idx = rp * 256 + tid;
            int loc = idx / TC, c = idx - loc * TC;
            const float* Yb = &sm[oY + loc * 8];
            float val;
            if constexpr (LAYER == 0) {
                if (c < 16) {
                    val = 0.28209479177387814f * sm[oF0 + loc * 16 + c];         // (0,0,0)
                } else {
                    int q = c - 16, v = q / 3, i2 = q - v * 3;                   // (1,0,1)
                    val = Yb[i2] * sm[oF0 + loc * 16 + v] * 0.5773502691896258f;
                }
            } else {
                if (c < 16) {
                    val = 0.28209479177387814f * sm[oF0 + loc * 16 + c];         // (0,0,0)
                } else if (c < 24) {
                    int v = c - 16;                                              // (0,1,1)
                    const float* f = &sm[oF1 + (loc * 8 + v) * 3];
                    val = (f[0] * Yb[0] + f[1] * Yb[1] + f[2] * Yb[2]) * 0.5773502691896258f;
                } else if (c < 72) {
                    int q = c - 24, v = q / 3, i2 = q - v * 3;                   // (1,0,1)
                    val = Yb[i2] * sm[oF0 + loc * 16 + v] * 0.5773502691896258f;
                } else if (c < 96) {
                    int q = c - 72, v = q / 3, i2 = q - v * 3;                   // (1,1,0)
                    val = sm[oF1 + (loc * 8 + v) * 3 + i2] * (0.28209479177387814f * 0.5773502691896258f);
                } else if (c < 120) {
                    int q = c - 96, v = q / 3, i2 = q - v * 3;                   // (1,1,1)
                    const float* f = &sm[oF1 + (loc * 8 + v) * 3];
                    int i1 = (i2 + 1) % 3, i3 = (i2 + 2) % 3;
                    val = (f[i1] * Yb[i3] - f[i3] * Yb[i1]) * 0.4082482904638631f;
                } else {
                    int q = c - 120, v = q / 3, i2 = q - v * 3;                  // (1,1,2)
                    const float* f = &sm[oF1 + (loc * 8 + v) * 3];
                    const float D  = 0.31622776601683794f;
                    const float Bc = 0.18257418583505536f;
                    float Y20 = Yb[3], Y21 = Yb[4], Y22 = Yb[5], Y23 = Yb[6], Y24 = Yb[7];
                    if (i2 == 0)      val = D * (Y20 * f[2] + Y21 * f[1]) - (Bc * Y22 + D * Y24) * f[0];
                    else if (i2 == 1) val = D * (Y21 * f[0] + Y23 * f[2]) + 2.0f * Bc * Y22 * f[1];
                    else              val = D * (Y20 * f[0] + Y23 * f[1] + Y24 * f[2]) - Bc * Y22 * f[2];
                }
            }
            sm[oA + loc * TCP + c] = val;
        }
    }
    __syncthreads();

    // ---------------- P3: M update, register tile R x C --------------------
    float acc[R][C];
#pragma unroll
    for (int rr = 0; rr < R; ++rr)
#pragma unroll
        for (int cc = 0; cc < C; ++cc) acc[rr][cc] = 0.0f;

    if constexpr (LAYER == 0) {
        const int hr = tid >> 4, cg = tid & 15;     // 16 row-groups x 16 col-groups
#pragma unroll 4
        for (int bl = 0; bl < NS; ++bl) {
            float2 hv = *(const float2*)&sm[oH + bl * 32 + hr * 2];
            float4 tv = *(const float4*)&sm[oA + bl * 64 + cg * 4];
            float hvv[2] = {hv.x, hv.y};
            float tvv[4] = {tv.x, tv.y, tv.z, tv.w};
#pragma unroll
            for (int rr = 0; rr < 2; ++rr)
#pragma unroll
                for (int cc = 0; cc < 4; ++cc) acc[rr][cc] += hvv[rr] * tvv[cc];
        }
    } else {
        const int hr = tid >> 5, cg = tid & 31;     // 8 row-groups x 32 col-groups
#pragma unroll 4
        for (int bl = 0; bl < NS; ++bl) {
            float4 hv = *(const float4*)&sm[oH + bl * 32 + hr * 4];
            const float* tp = &sm[oA + bl * TCP + cg * 5];
            float hvv[4] = {hv.x, hv.y, hv.z, hv.w};
            float t0 = tp[0], t1 = tp[1], t2 = tp[2], t3 = tp[3], t4 = tp[4];
#pragma unroll
            for (int rr = 0; rr < 4; ++rr) {
                acc[rr][0] += hvv[rr] * t0;
                acc[rr][1] += hvv[rr] * t1;
                acc[rr][2] += hvv[rr] * t2;
                acc[rr][3] += hvv[rr] * t3;
                acc[rr][4] += hvv[rr] * t4;
            }
        }
    }
    __syncthreads();   // all tC reads done before M overwrites region A

    {
        const int hr = (LAYER == 0) ? (tid >> 4) : (tid >> 5);
        const int cg = (LAYER == 0) ? (tid & 15) : (tid & 31);
#pragma unroll
        for (int rr = 0; rr < R; ++rr)
#pragma unroll
            for (int cc = 0; cc < C; ++cc) {
                int col = cg * C + cc;
                if (col < TC) sm[oA + (hr * R + rr) * MSTRE + col] = acc[rr][cc];
            }
    }
    __syncthreads();

    // ---------------- P4: epilogue: contract M with wout -------------------
    constexpr int oU = oA + 32 * MSTRE;
    constexpr int NITEM = NOUT * 32;
    for (int rp = 0; rp < NITEM / 256; ++rp) {
        int idx = rp * 256 + tid;
        int h = idx / NOUT, o = idx - h * NOUT;
        const float* wr = &wout[h * TW];
        const float* mr = &sm[oA + h * MSTRE];
        float U;
        if constexpr (LAYER == 0) {
            const float sc = I32 * 0.25f;
            float accv = 0.0f;
            if (o < 24) {
#pragma unroll
                for (int v = 0; v < 16; ++v) accv += wr[o * 16 + v] * mr[v];
            } else {
                int j = o - 24, u = j / 3, i2 = j - u * 3;
#pragma unroll
                for (int v = 0; v < 16; ++v) accv += wr[384 + u * 16 + v] * mr[16 + v * 3 + i2];
            }
            U = accv * sc;
        } else if constexpr (LAYER == 1) {
            float aA = 0.0f, aB = 0.0f;
            if (o < 24) {
#pragma unroll
                for (int v = 0; v < 16; ++v) aA += wr[o * 16 + v] * mr[v];
#pragma unroll
                for (int v = 0; v < 8; ++v) aB += wr[384 + o * 8 + v] * mr[16 + v];
                U = (aA * I32 + aB * 0.25f) * I32;
            } else {
                int j = o - 24, u = j / 3, i2 = j - u * 3;
#pragma unroll
                for (int v = 0; v < 16; ++v) aA += wr[576 + u * 16 + v] * mr[24 + v * 3 + i2];
#pragma unroll
                for (int v = 0; v < 8; ++v)
                    aB += wr[704 + u * 8 + v] * mr[72 + v * 3 + i2]
                        + wr[768 + u * 8 + v] * mr[96 + v * 3 + i2]
                        + wr[832 + u * 8 + v] * mr[120 + v * 3 + i2];
                U = (aA * 0.125f + aB * I32) * I32;
            }
        } else {  // LAYER == 2
            float aA = 0.0f, aB = 0.0f;
            if (o < 2) {
#pragma unroll
                for (int v = 0; v < 16; ++v) aA += wr[o * 16 + v] * mr[v];
#pragma unroll
                for (int v = 0; v < 8; ++v) aB += wr[32 + o * 8 + v] * mr[16 + v];
                U = (aA * I32 + aB * 0.25f) * I32;
            } else {
                int j = o - 2, u = j / 3, i2 = j - u * 3;
#pragma unroll
                for (int v = 0; v < 16; ++v) aA += wr[48 + u * 16 + v] * mr[24 + v * 3 + i2];
#pragma unroll
                for (int v = 0; v < 8; ++v)
                    aB += wr[80 + u * 8 + v] * mr[72 + v * 3 + i2]
                        + wr[96 + u * 8 + v] * mr[96 + v * 3 + i2]
                        + wr[112 + u * 8 + v] * mr[120 + v * 3 + i2];
                U = (aA * 0.125f + aB * I32) * I32;
            }
        }
        sm[oU + o * 33 + h] = U;
    }
    __syncthreads();

    if (tid < NOUT) {
        float su = 0.0f;
#pragma unroll
        for (int h = 0; h < 32; ++h) su += sm[oU + tid * 33 + h];
        part[blk * NOUT + tid] = su;
    }
}

// ---------------------------------------------------------------------------
// Final sum: out[atom][2*4] interleaved from 4 split partials of layer 2.
// ---------------------------------------------------------------------------
__global__ __launch_bounds__(256) void tfn_fin(
    const float* __restrict__ part2, float* __restrict__ out)
{
    int t = blockIdx.x * 256 + threadIdx.x;  // < BB*NN*8
    int atom = t >> 3, o = t & 7;
    const float* p = &part2[atom * SPLIT * 8];
    float su = p[o] + p[8 + o] + p[16 + o] + p[24 + o];
    int pos;
    if (o < 2) pos = o * 4;
    else { int j = o - 2; pos = (j / 3) * 4 + 1 + (j - (j / 3) * 3); }
    out[atom * 8 + pos] = su;
}

// ---------------------------------------------------------------------------
// Fallback: verified round-1 monolithic kernel (used only if ws too small).
// ---------------------------------------------------------------------------
template <int LAYER>
__global__ __launch_bounds__(256) void tfn_layer_mono(
    const float* __restrict__ geo,
    const float* __restrict__ fin0,
    const float* __restrict__ fin1,
    const float* __restrict__ w0,
    const float* __restrict__ b0g,
    const float* __restrict__ wout,
    float* __restrict__ o0,
    float* __restrict__ o1)
{
    constexpr int TC   = (LAYER == 0) ? 64 : 144;
    constexpr int TW   = (LAYER == 0) ? 512 : (LAYER == 1 ? 896 : 128);
    constexpr int CPT  = TC / 8;
    constexpr int CPTT = TC / 16;

    const int tid = threadIdx.x;
    const int blk = blockIdx.x;
    const int z = blk / NN, a = blk % NN;

    __shared__ float geoL[NN * 3];
    __shared__ float f0L[NN * 16];
    __shared__ float f1L[(LAYER == 0) ? 1 : (NN * 24)];
    __shared__ float w0L[NBASIS * HHID];
    __shared__ float b0L[HHID];
    __shared__ float YC[16 * 8];
    __shared__ float basC[16 * NBASIS];
    __shared__ float hC[16 * HHID];
    __shared__ float tC[16 * TC];
    __shared__ float Mlds[HHID * TC];
    __shared__ float outS[32];

    const float s = S_SCALE;

    for (int i = tid; i < NN * 3; i += 256) geoL[i] = geo[z * NN * 3 + i];
    for (int i = tid; i < NN * 16; i += 256) {
        float v = fin0[z * NN * 16 + i];
        if (LAYER == 0) v *= s;
        f0L[i] = v;
    }
    if constexpr (LAYER != 0) {
        for (int i = tid; i < NN * 24; i += 256) f1L[i] = fin1[z * NN * 24 + i];
    }
    for (int i = tid; i < NBASIS * HHID; i += 256) w0L[i] = w0[i];
    if (tid < HHID) b0L[tid] = b0g[tid];
    __syncthreads();

    const float ax = geoL[a * 3 + 0], ay = geoL[a * 3 + 1], az = geoL[a * 3 + 2];

    float Macc[CPT];
#pragma unroll
    for (int j = 0; j < CPT; ++j) Macc[j] = 0.0f;
    const int hh  = tid >> 3;
    const int cg0 = (tid & 7) * CPT;

    for (int cb = 0; cb < NN / 16; ++cb) {
        {
            const int bl = tid & 15, item = tid >> 4;
            const int b = cb * 16 + bl;
            float rx = ax - geoL[b * 3 + 0];
            float ry = ay - geoL[b * 3 + 1];
            float rz = az - geoL[b * 3 + 2];
            float r = sqrtf(rx * rx + ry * ry + rz * rz + 1e-12f);
            float inv = 1.0f / fmaxf(r, 1e-6f);
            float ux = rx * inv, uy = ry * inv, uz = rz * inv;
            if (item < NBASIS) {
                float dg = r * 2.25f - (float)item;
                float bas = 0.0f;
                if (fabsf(dg) < 1.0f) {
                    float cc = cosf(1.5707963267948966f * dg);
                    bas = cc * cc;
                }
                basC[bl * NBASIS + item] = bas;
            } else if (item == 10) {
                YC[bl * 8 + 0] = 0.4886025119029199f * uy;
                YC[bl * 8 + 1] = 0.4886025119029199f * uz;
                YC[bl * 8 + 2] = 0.4886025119029199f * ux;
            } else if (item == 11) {
                YC[bl * 8 + 3] = 1.0925484305920792f * ux * uy;
                YC[bl * 8 + 4] = 1.0925484305920792f * uy * uz;
                YC[bl * 8 + 5] = 0.31539156525252005f * (2.0f * uz * uz - ux * ux - uy * uy);
                YC[bl * 8 + 6] = 1.0925484305920792f * ux * uz;
                YC[bl * 8 + 7] = 0.5462742152960396f * (ux * ux - uy * uy);
            }
        }
        __syncthreads();

#pragma unroll
        for (int rep = 0; rep < 2; ++rep) {
            int idx = tid + rep * 256;
            int bl = idx >> 5, h2 = idx & 31;
            float su = 0.0f;
#pragma unroll
            for (int k = 0; k < NBASIS; ++k) su += basC[bl * NBASIS + k] * w0L[k * HHID + h2];
            hC[bl * HHID + h2] = relu_r(su * ISQ10 + b0L[h2]);
        }

        {
            const int bl = tid >> 4, cg = tid & 15;
            const int b = cb * 16 + bl;
            const float* Yb = &YC[bl * 8];
#pragma unroll
            for (int jj = 0; jj < CPTT; ++jj) {
                int c = cg * CPTT + jj;
                float val;
                if constexpr (LAYER == 0) {
                    if (c < 16) {
                        val = 0.28209479177387814f * f0L[b * 16 + c];
                    } else {
                        int q = c - 16, v = q / 3, i2 = q % 3;
                        val = Yb[i2] * f0L[b * 16 + v] * 0.5773502691896258f;
                    }
                } else {
                    if (c < 16) {
                        val = 0.28209479177387814f * f0L[b * 16 + c];
                    } else if (c < 24) {
                        int v = c - 16;
                        const float* f = &f1L[(b * 8 + v) * 3];
                        val = (f[0] * Yb[0] + f[1] * Yb[1] + f[2] * Yb[2]) * 0.5773502691896258f;
                    } else if (c < 72) {
                        int q = c - 24, v = q / 3, i2 = q % 3;
                        val = Yb[i2] * f0L[b * 16 + v] * 0.5773502691896258f;
                    } else if (c < 96) {
                        int q = c - 72, v = q / 3, i2 = q % 3;
                        val = f1L[(b * 8 + v) * 3 + i2] * (0.28209479177387814f * 0.5773502691896258f);
                    } else if (c < 120) {
                        int q = c - 96, v = q / 3, i2 = q % 3;
                        const float* f = &f1L[(b * 8 + v) * 3];
                        int i1 = (i2 + 1) % 3, i3 = (i2 + 2) % 3;
                        val = (f[i1] * Yb[i3] - f[i3] * Yb[i1]) * 0.4082482904638631f;
                    } else {
                        int q = c - 120, v = q / 3, i2 = q % 3;
                        const float* f = &f1L[(b * 8 + v) * 3];
                        const float D = 0.31622776601683794f;
                        const float Bc = 0.18257418583505536f;
                        float Y20 = Yb[3], Y21 = Yb[4], Y22 = Yb[5], Y23 = Yb[6], Y24 = Yb[7];
                        if (i2 == 0)      val = D * (Y20 * f[2] + Y21 * f[1]) - (Bc * Y22 + D * Y24) * f[0];
                        else if (i2 == 1) val = D * (Y21 * f[0] + Y23 * f[2]) + 2.0f * Bc * Y22 * f[1];
                        else              val = D * (Y20 * f[0] + Y23 * f[1] + Y24 * f[2]) - Bc * Y22 * f[2];
                    }
                }
                tC[bl * TC + c] = val;
            }
        }
        __syncthreads();

#pragma unroll 4
        for (int bl = 0; bl < 16; ++bl) {
            float hv = hC[bl * HHID + hh];
#pragma unroll
            for (int j = 0; j < CPT; ++j) Macc[j] += hv * tC[bl * TC + cg0 + j];
        }
        __syncthreads();
    }

#pragma unroll
    for (int j = 0; j < CPT; ++j) Mlds[hh * TC + cg0 + j] = Macc[j];
    __syncthreads();

    const float i32 = I32;

    if constexpr (LAYER == 0) {
        const float sc = i32 * 0.25f;
        float o1v = 0.0f;
        if (tid < 24) {
            float acc = 0.0f;
            for (int h2 = 0; h2 < 32; ++h2) {
                const float* wr = &wout[h2 * TW + tid * 16];
                const float* mr = &Mlds[h2 * TC];
#pragma unroll
                for (int v = 0; v < 16; ++v) acc += wr[v] * mr[v];
            }
            outS[tid] = acc * sc;
        } else if (tid >= 32 && tid < 56) {
            int idx = tid - 32, u = idx / 3, i2 = idx % 3;
            float acc = 0.0f;
            for (int h2 = 0; h2 < 32; ++h2) {
                const float* wr = &wout[h2 * TW + 384 + u * 16];
                const float* mr = &Mlds[h2 * TC + 16 + i2];
#pragma unroll
                for (int v = 0; v < 16; ++v) acc += wr[v] * mr[v * 3];
            }
            o1v = acc * sc;
        }
        __syncthreads();
        if (tid < 16) {
            o0[(z * NN + a) * 16 + tid] = relu_r(outS[tid]) * s;
        } else if (tid >= 32 && tid < 56) {
            int idx = tid - 32, u = idx / 3, i2 = idx % 3;
            float g = sigmoid_r(outS[16 + u]);
            o1[((z * NN + a) * 8 + u) * 3 + i2] = o1v * g * s;
        }
    } else if constexpr (LAYER == 1) {
        float o1v = 0.0f;
        if (tid < 24) {
            float aA = 0.0f, aB = 0.0f;
            for (int h2 = 0; h2 < 32; ++h2) {
                const float* wr = &wout[h2 * TW];
                const float* mr = &Mlds[h2 * TC];
#pragma unroll
                for (int v = 0; v < 16; ++v) aA += wr[tid * 16 + v] * mr[v];
#pragma unroll
                for (int v = 0; v < 8; ++v) aB += wr[384 + tid * 8 + v] * mr[16 + v];
            }
            outS[tid] = (aA * i32 + aB * 0.25f) * i32;
        } else if (tid >= 32 && tid < 56) {
            int idx = tid - 32, u = idx / 3, i2 = idx % 3;
            float aA = 0.0f, aB = 0.0f;
            for (int h2 = 0; h2 < 32; ++h2) {
                const float* wr = &wout[h2 * TW];
                const float* mr = &Mlds[h2 * TC];
#pragma unroll
                for (int v = 0; v < 16; ++v) aA += wr[576 + u * 16 + v] * mr[24 + v * 3 + i2];
#pragma unroll
                for (int v = 0; v < 8; ++v)
                    aB += wr[704 + u * 8 + v] * mr[72 + v * 3 + i2]
                        + wr[768 + u * 8 + v] * mr[96 + v * 3 + i2]
                        + wr[832 + u * 8 + v] * mr[120 + v * 3 + i2];
            }
            o1v = (aA * 0.125f + aB * i32) * i32;
        }
        __syncthreads();
        if (tid < 16) {
            o0[(z * NN + a) * 16 + tid] = relu_r(outS[tid]) * s;
        } else if (tid >= 32 && tid < 56) {
            int idx = tid - 32, u = idx / 3, i2 = idx % 3;
            float g = sigmoid_r(outS[16 + u]);
            o1[((z * NN + a) * 8 + u) * 3 + i2] = o1v * g * s;
        }
    } else {
        if (tid < 2) {
            float aA = 0.0f, aB = 0.0f;
            for (int h2 = 0; h2 < 32; ++h2) {
                const float* wr = &wout[h2 * TW];
                const float* mr = &Mlds[h2 * TC];
#pragma unroll
                for (int v = 0; v < 16; ++v) aA += wr[tid * 16 + v] * mr[v];
#pragma unroll
                for (int v = 0; v < 8; ++v) aB += wr[32 + tid * 8 + v] * mr[16 + v];
            }
            o0[(z * NN + a) * 8 + tid * 4] = (aA * i32 + aB * 0.25f) * i32;
        } else if (tid >= 32 && tid < 38) {
            int idx = tid - 32, u = idx / 3, i2 = idx % 3;
            float aA = 0.0f, aB = 0.0f;
            for (int h2 = 0; h2 < 32; ++h2) {
                const float* wr = &wout[h2 * TW];
                const float* mr = &Mlds[h2 * TC];
#pragma unroll
                for (int v = 0; v < 16; ++v) aA += wr[48 + u * 16 + v] * mr[24 + v * 3 + i2];
#pragma unroll
                for (int v = 0; v < 8; ++v)
                    aB += wr[80 + u * 8 + v] * mr[72 + v * 3 + i2]
                        + wr[96 + u * 8 + v] * mr[96 + v * 3 + i2]
                        + wr[112 + u * 8 + v] * mr[120 + v * 3 + i2];
            }
            o0[(z * NN + a) * 8 + u * 4 + 1 + i2] = (aA * 0.125f + aB * i32) * i32;
        }
    }
}

extern "C" void kernel_launch(void* const* d_in, const int* in_sizes, int n_in,
                              void* d_out, int out_size, void* d_ws, size_t ws_size,
                              hipStream_t stream) {
    const float* features = (const float*)d_in[0];
    const float* geometry = (const float*)d_in[1];
    const float* c0w0   = (const float*)d_in[2];
    const float* c0b0   = (const float*)d_in[3];
    const float* c0wout = (const float*)d_in[4];
    const float* c1w0   = (const float*)d_in[5];
    const float* c1b0   = (const float*)d_in[6];
    const float* c1wout = (const float*)d_in[7];
    const float* c2w0   = (const float*)d_in[8];
    const float* c2b0   = (const float*)d_in[9];
    const float* c2wout = (const float*)d_in[10];
    float* out = (float*)d_out;

    float* ws = (float*)d_ws;
    const size_t NBLK = (size_t)BB * NN * SPLIT;                 // 1536
    const size_t need = NBLK * 48 * 2 + NBLK * 8;                // partA, partB, part2

    if (ws_size >= need * sizeof(float)) {
        float* partA = ws;
        float* partB = partA + NBLK * 48;
        float* part2 = partB + NBLK * 48;

        dim3 g1((unsigned)NBLK), blk(256);
        hipLaunchKernelGGL((tfn_s1<0>), g1, blk, 0, stream,
                           features, geometry, c0w0, c0b0, c0wout, partA);
        hipLaunchKernelGGL((tfn_s1<1>), g1, blk, 0, stream,
                           partA, geometry, c1w0, c1b0, c1wout, partB);
        hipLaunchKernelGGL((tfn_s1<2>), g1, blk, 0, stream,
                           partB, geometry, c2w0, c2b0, c2wout, part2);
        hipLaunchKernelGGL(tfn_fin, dim3(BB * NN * 8 / 256), blk, 0, stream,
                           part2, out);
    } else {
        float* f0a = ws;
        float* f1a = f0a + BB * NN * 16;
        float* f0b = f1a + BB * NN * 24;
        float* f1b = f0b + BB * NN * 16;
        dim3 grid(BB * NN), blk(256);
        hipLaunchKernelGGL((tfn_layer_mono<0>), grid, blk, 0, stream,
                           geometry, features, nullptr, c0w0, c0b0, c0wout, f0a, f1a);
        hipLaunchKernelGGL((tfn_layer_mono<1>), grid, blk, 0, stream,
                           geometry, f0a, f1a, c1w0, c1b0, c1wout, f0b, f1b);
        hipLaunchKernelGGL((tfn_layer_mono<2>), grid, blk, 0, stream,
                           geometry, f0b, f1b, c2w0, c2b0, c2wout, out, nullptr);
    }
}